// Round 3
// baseline (147.719 us; speedup 1.0000x reference)
//
#include <hip/hip_runtime.h>
#include <hip/hip_bf16.h>

#define CIN 8
#define IMG 224
#define PS 16
#define HP 14
#define D_ 768
#define HID 128
#define MPT 196      // Hp*Wp
#define K_ 256       // PS*PS
#define WSIZE 196608 // D_*K_
#define NJ 197376    // WSIZE + D_

typedef __bf16 bf16x8 __attribute__((ext_vector_type(8)));
typedef float f32x4 __attribute__((ext_vector_type(4)));

static __device__ __forceinline__ ushort f2bf(float f) {
  union { float f; unsigned int u; } x; x.f = f;
  unsigned int r = x.u + 0x7fffu + ((x.u >> 16) & 1u);
  return (ushort)(r >> 16);
}

// async global -> LDS, 16B per lane. LDS base wave-uniform; global addr per-lane.
static __device__ __forceinline__ void gload16(const void* g, void* l) {
  __builtin_amdgcn_global_load_lds(
      (const __attribute__((address_space(1))) unsigned int*)(uintptr_t)g,
      (__attribute__((address_space(3))) unsigned int*)(uintptr_t)l, 16, 0, 0);
}

// ---------- k1: ht[i][c] = relu(ce @ fc1_w + b1), 4-way K-split per block
__global__ __launch_bounds__(512) void k1_fc1(const float* __restrict__ ce,
                                              const float* __restrict__ w1,
                                              const float* __restrict__ b1,
                                              float* __restrict__ ht) {
  __shared__ float sh[3][HID];
  int c = blockIdx.x;
  int t = threadIdx.x;
  int i = t & 127, ksp = t >> 7;
  const float* cev = ce + c * D_ + ksp * 192;
  const float* wp = w1 + (size_t)(ksp * 192) * HID + i;
  float acc = 0.f;
#pragma unroll 8
  for (int d = 0; d < 192; ++d) acc = fmaf(cev[d], wp[(size_t)d * HID], acc);
  if (ksp) sh[ksp - 1][i] = acc;
  __syncthreads();
  if (ksp == 0) {
    float s = b1[i] + acc + sh[0][i] + sh[1][i] + sh[2][i];
    ht[i * CIN + c] = fmaxf(s, 0.f);
  }
}

// ---------- k2: y = tanh(h@fc2_w + b2); scatter wts(bf16, [c][d*256+k]) + bias(fp32)
// 1 column/thread, 771 blocks (NJ = 771*256 exactly)
__global__ __launch_bounds__(256) void k2_fc2(
    const float* __restrict__ ht, const float* __restrict__ w2,
    const float* __restrict__ b2, ushort* __restrict__ wbf,
    float* __restrict__ biasOut) {
  int t = threadIdx.x;
  int j = blockIdx.x * 256 + t;
  const float* wp = w2 + j;
  const float4* ht4 = (const float4*)ht;  // uniform index -> scalar loads
  float4 a0 = {0, 0, 0, 0}, a1 = {0, 0, 0, 0};
#pragma unroll 8
  for (int i = 0; i < HID; ++i) {
    float wv = wp[(size_t)i * NJ];
    float4 hA = ht4[i * 2], hB = ht4[i * 2 + 1];
    a0.x = fmaf(hA.x, wv, a0.x); a0.y = fmaf(hA.y, wv, a0.y);
    a0.z = fmaf(hA.z, wv, a0.z); a0.w = fmaf(hA.w, wv, a0.w);
    a1.x = fmaf(hB.x, wv, a1.x); a1.y = fmaf(hB.y, wv, a1.y);
    a1.z = fmaf(hB.z, wv, a1.z); a1.w = fmaf(hB.w, wv, a1.w);
  }
  float bb = b2[j];
  if (j < WSIZE) {
    wbf[(size_t)0 * WSIZE + j] = f2bf(tanhf(a0.x + bb));
    wbf[(size_t)1 * WSIZE + j] = f2bf(tanhf(a0.y + bb));
    wbf[(size_t)2 * WSIZE + j] = f2bf(tanhf(a0.z + bb));
    wbf[(size_t)3 * WSIZE + j] = f2bf(tanhf(a0.w + bb));
    wbf[(size_t)4 * WSIZE + j] = f2bf(tanhf(a1.x + bb));
    wbf[(size_t)5 * WSIZE + j] = f2bf(tanhf(a1.y + bb));
    wbf[(size_t)6 * WSIZE + j] = f2bf(tanhf(a1.z + bb));
    wbf[(size_t)7 * WSIZE + j] = f2bf(tanhf(a1.w + bb));
  } else {
    int jb = j - WSIZE;
    biasOut[0 * D_ + jb] = tanhf(a0.x + bb);
    biasOut[1 * D_ + jb] = tanhf(a0.y + bb);
    biasOut[2 * D_ + jb] = tanhf(a0.z + bb);
    biasOut[3 * D_ + jb] = tanhf(a0.w + bb);
    biasOut[4 * D_ + jb] = tanhf(a1.x + bb);
    biasOut[5 * D_ + jb] = tanhf(a1.y + bb);
    biasOut[6 * D_ + jb] = tanhf(a1.z + bb);
    biasOut[7 * D_ + jb] = tanhf(a1.w + bb);
  }
}

// ---------- k3: per-channel GEMM. B staged ONCE (64KB, XOR-swizzled, rule 21);
// A read directly from fp32 x (L1/L2-served) + in-reg bf16 cast. One barrier total.
__global__ __launch_bounds__(256, 2) void k3_gemm(
    const float* __restrict__ x, const ushort* __restrict__ wbf,
    const float* __restrict__ bias, float* __restrict__ out) {
  __shared__ ushort Bs[128 * 256];  // physical part q at (row,q) holds logical p = (q&16)|((q^row)&15)

  int bid = blockIdx.x;
  int c = bid & 7;            // channel == XCD: x slice + 384KB weights L2-resident
  int rem = bid >> 3;
  int mt = rem / 6;
  int nt = rem - mt * 6;      // 6 siblings share the A rows within one XCD
  int m0 = mt * 128, n0 = nt * 128;

  int t = threadIdx.x;
  int lane = t & 63;
  int w = t >> 6;
  int wr = w >> 1, wc = w & 1;
  int rB = lane & 15;
  int h = lane >> 4;          // k-subchunk selector

  const ushort* wsrc = wbf + (size_t)c * WSIZE + (size_t)n0 * K_;

  // ---- A row pointers (fp32 x), one per mi fragment; include per-lane k-sub-offset
  int hb = (h >> 1) * IMG + (h & 1) * 8;   // krow=(h>>1), kcol=(h&1)*8
  const float* ap[4];
#pragma unroll
  for (int mi = 0; mi < 4; ++mi) {
    int rowA = m0 + wr * 64 + mi * 16 + rB;
    int b = rowA / MPT;
    int hw = rowA - b * MPT;
    int hp = hw / HP;
    int wp = hw - hp * HP;
    ap[mi] = x + ((size_t)(b * CIN + c) * IMG + hp * PS) * IMG + wp * PS + hb;
  }

  // ---- preload A step (ks=0,kc=0) so its latency hides under B staging drain
  float4 pf0[4], pf1[4];
#pragma unroll
  for (int mi = 0; mi < 4; ++mi) {
    pf0[mi] = *(const float4*)(ap[mi]);
    pf1[mi] = *(const float4*)(ap[mi] + 4);
  }

  // ---- stage whole B tile (128 x 256 bf16 = 64KB), source carries inverse swizzle
#pragma unroll
  for (int i = 0; i < 16; ++i) {
    int g = i * 256 + t;
    int row = g >> 5;
    int q = t & 31;
    int p = (q & 16) | ((q ^ row) & 15);
    gload16(wsrc + row * K_ + p * 8, &Bs[i * 2048 + w * 512]);
  }
  __syncthreads();

  f32x4 acc[4][4] = {};

#pragma unroll
  for (int ks = 0; ks < 4; ++ks) {
#pragma unroll
    for (int kc = 0; kc < 2; ++kc) {
      bf16x8 af[4], bq[4];
#pragma unroll
      for (int mi = 0; mi < 4; ++mi) {
        float4 f0, f1;
        if (ks == 0 && kc == 0) { f0 = pf0[mi]; f1 = pf1[mi]; }
        else {
          const float* s = ap[mi] + (ks * 4 + kc * 2) * IMG;
          f0 = *(const float4*)s;
          f1 = *(const float4*)(s + 4);
        }
        union { ushort u[8]; bf16x8 v; } pk;
        pk.u[0] = f2bf(f0.x); pk.u[1] = f2bf(f0.y); pk.u[2] = f2bf(f0.z); pk.u[3] = f2bf(f0.w);
        pk.u[4] = f2bf(f1.x); pk.u[5] = f2bf(f1.y); pk.u[6] = f2bf(f1.z); pk.u[7] = f2bf(f1.w);
        af[mi] = pk.v;
      }
      int pc = ks * 8 + kc * 4;                 // logical part = pc + h
      int tq = ((pc & 15) + h) ^ rB;            // swizzled low-4
      int qoff = ((pc & 16) << 3) + tq * 8;     // element offset within row
#pragma unroll
      for (int ni = 0; ni < 4; ++ni)
        bq[ni] = *(const bf16x8*)&Bs[(wc * 64 + ni * 16 + rB) * 256 + qoff];
#pragma unroll
      for (int mi = 0; mi < 4; ++mi)
#pragma unroll
        for (int ni = 0; ni < 4; ++ni)
          acc[mi][ni] = __builtin_amdgcn_mfma_f32_16x16x32_bf16(af[mi], bq[ni], acc[mi][ni], 0, 0, 0);
    }
  }

  // ---- epilogue: + bias.  C/D: col = lane&15, row = (lane>>4)*4 + reg
  int col_l = rB;
  int rowg = h;
  float bv[4];
#pragma unroll
  for (int ni = 0; ni < 4; ++ni)
    bv[ni] = bias[c * D_ + n0 + wc * 64 + ni * 16 + col_l];
#pragma unroll
  for (int mi = 0; mi < 4; ++mi) {
#pragma unroll
    for (int r = 0; r < 4; ++r) {
      int mrow = m0 + wr * 64 + mi * 16 + rowg * 4 + r;
      int b2 = mrow / MPT;
      int hw2 = mrow - b2 * MPT;
      float* op = out + ((size_t)b2 * (CIN * MPT) + c * MPT + hw2) * D_ + n0 + wc * 64 + col_l;
#pragma unroll
      for (int ni = 0; ni < 4; ++ni)
        op[ni * 16] = acc[mi][ni][r] + bv[ni];
    }
  }
}

extern "C" void kernel_launch(void* const* d_in, const int* in_sizes, int n_in,
                              void* d_out, int out_size, void* d_ws, size_t ws_size,
                              hipStream_t stream) {
  const float* x  = (const float*)d_in[0];
  const float* ce = (const float*)d_in[2];
  const float* w1 = (const float*)d_in[3];
  const float* b1 = (const float*)d_in[4];
  const float* w2 = (const float*)d_in[5];
  const float* b2 = (const float*)d_in[6];
  float* out = (float*)d_out;

  char* ws = (char*)d_ws;
  float*  ht      = (float*)ws;                    // 128*8*4   = 4096 B  (transposed h)
  float*  biasOut = (float*)(ws + 4096);           // 8*768*4   = 24576 B
  ushort* wbf     = (ushort*)(ws + 4096 + 24576);  // 8*196608*2 = 3145728 B

  k1_fc1<<<dim3(CIN), dim3(512), 0, stream>>>(ce, w1, b1, ht);
  k2_fc2<<<dim3(NJ / 256), dim3(256), 0, stream>>>(ht, w2, b2, wbf, biasOut);
  k3_gemm<<<dim3(8 * 49 * 6), dim3(256), 0, stream>>>(x, wbf, biasOut, out);
}

// Round 4
// 112.093 us; speedup vs baseline: 1.3178x; 1.3178x over previous
//
#include <hip/hip_runtime.h>
#include <hip/hip_bf16.h>

#define CIN 8
#define IMG 224
#define PS 16
#define HP 14
#define D_ 768
#define HID 128
#define MPT 196      // Hp*Wp
#define K_ 256       // PS*PS
#define WSIZE 196608 // D_*K_
#define NJ 197376    // WSIZE + D_

typedef __bf16 bf16x8 __attribute__((ext_vector_type(8)));
typedef float f32x4 __attribute__((ext_vector_type(4)));

static __device__ __forceinline__ ushort f2bf(float f) {
  union { float f; unsigned int u; } x; x.f = f;
  unsigned int r = x.u + 0x7fffu + ((x.u >> 16) & 1u);
  return (ushort)(r >> 16);
}

// async global -> LDS, 16B per lane. LDS base wave-uniform; global addr per-lane.
static __device__ __forceinline__ void gload16(const void* g, void* l) {
  __builtin_amdgcn_global_load_lds(
      (const __attribute__((address_space(1))) unsigned int*)(uintptr_t)g,
      (__attribute__((address_space(3))) unsigned int*)(uintptr_t)l, 16, 0, 0);
}

// ---------- k1: ht[i][c] = relu(ce @ fc1_w + b1), 4-way K-split per block
__global__ __launch_bounds__(512) void k1_fc1(const float* __restrict__ ce,
                                              const float* __restrict__ w1,
                                              const float* __restrict__ b1,
                                              float* __restrict__ ht) {
  __shared__ float sh[3][HID];
  int c = blockIdx.x;
  int t = threadIdx.x;
  int i = t & 127, ksp = t >> 7;
  const float* cev = ce + c * D_ + ksp * 192;
  const float* wp = w1 + (size_t)(ksp * 192) * HID + i;
  float acc = 0.f;
#pragma unroll 8
  for (int d = 0; d < 192; ++d) acc = fmaf(cev[d], wp[(size_t)d * HID], acc);
  if (ksp) sh[ksp - 1][i] = acc;
  __syncthreads();
  if (ksp == 0) {
    float s = b1[i] + acc + sh[0][i] + sh[1][i] + sh[2][i];
    ht[i * CIN + c] = fmaxf(s, 0.f);
  }
}

// ---------- k2: y = tanh(h@fc2_w + b2); scatter wts(bf16, [c][d*256+k]) + bias(fp32)
// 1 column/thread, 771 blocks (NJ = 771*256 exactly)
__global__ __launch_bounds__(256) void k2_fc2(
    const float* __restrict__ ht, const float* __restrict__ w2,
    const float* __restrict__ b2, ushort* __restrict__ wbf,
    float* __restrict__ biasOut) {
  int t = threadIdx.x;
  int j = blockIdx.x * 256 + t;
  const float* wp = w2 + j;
  const float4* ht4 = (const float4*)ht;  // uniform index -> scalar loads
  float4 a0 = {0, 0, 0, 0}, a1 = {0, 0, 0, 0};
#pragma unroll 8
  for (int i = 0; i < HID; ++i) {
    float wv = wp[(size_t)i * NJ];
    float4 hA = ht4[i * 2], hB = ht4[i * 2 + 1];
    a0.x = fmaf(hA.x, wv, a0.x); a0.y = fmaf(hA.y, wv, a0.y);
    a0.z = fmaf(hA.z, wv, a0.z); a0.w = fmaf(hA.w, wv, a0.w);
    a1.x = fmaf(hB.x, wv, a1.x); a1.y = fmaf(hB.y, wv, a1.y);
    a1.z = fmaf(hB.z, wv, a1.z); a1.w = fmaf(hB.w, wv, a1.w);
  }
  float bb = b2[j];
  if (j < WSIZE) {
    wbf[(size_t)0 * WSIZE + j] = f2bf(tanhf(a0.x + bb));
    wbf[(size_t)1 * WSIZE + j] = f2bf(tanhf(a0.y + bb));
    wbf[(size_t)2 * WSIZE + j] = f2bf(tanhf(a0.z + bb));
    wbf[(size_t)3 * WSIZE + j] = f2bf(tanhf(a0.w + bb));
    wbf[(size_t)4 * WSIZE + j] = f2bf(tanhf(a1.x + bb));
    wbf[(size_t)5 * WSIZE + j] = f2bf(tanhf(a1.y + bb));
    wbf[(size_t)6 * WSIZE + j] = f2bf(tanhf(a1.z + bb));
    wbf[(size_t)7 * WSIZE + j] = f2bf(tanhf(a1.w + bb));
  } else {
    int jb = j - WSIZE;
    biasOut[0 * D_ + jb] = tanhf(a0.x + bb);
    biasOut[1 * D_ + jb] = tanhf(a0.y + bb);
    biasOut[2 * D_ + jb] = tanhf(a0.z + bb);
    biasOut[3 * D_ + jb] = tanhf(a0.w + bb);
    biasOut[4 * D_ + jb] = tanhf(a1.x + bb);
    biasOut[5 * D_ + jb] = tanhf(a1.y + bb);
    biasOut[6 * D_ + jb] = tanhf(a1.z + bb);
    biasOut[7 * D_ + jb] = tanhf(a1.w + bb);
  }
}

// ---------- k3: per-channel GEMM. FULL tile staged once (A 64KB + B 64KB LDS),
// ONE barrier, then pure LDS->MFMA loop. 512 threads = 8 waves (2M x 4N).
// Swizzle (both A and B): physical part pp = (lp&16) | ((lp ^ row)&15)  [involution]
__global__ __launch_bounds__(512, 1) void k3_gemm(
    const float* __restrict__ x, const ushort* __restrict__ wbf,
    const float* __restrict__ bias, float* __restrict__ out) {
  __shared__ ushort As[128 * 256];
  __shared__ ushort Bs[128 * 256];

  int bid = blockIdx.x;
  int c = bid & 7;            // channel == XCD: x slice + 384KB weights L2-resident
  int rem = bid >> 3;
  int mt = rem / 6;
  int nt = rem - mt * 6;      // 6 siblings share A rows within one XCD
  int m0 = mt * 128, n0 = nt * 128;

  int t = threadIdx.x;
  int lane = t & 63;
  int w = t >> 6;             // 0..7
  int wr = w >> 2, wc = w & 3;  // 2 x 4 wave grid
  int rB = lane & 15;
  int h = lane >> 4;

  const ushort* wsrc = wbf + (size_t)c * WSIZE + (size_t)n0 * K_;

  // ---- stage B: 8 x global_load_lds per thread, source carries inverse swizzle
#pragma unroll
  for (int i = 0; i < 8; ++i) {
    int row = i * 16 + (t >> 5);        // (i*512+t)>>5
    int q = t & 31;
    int p = (q & 16) | ((q ^ row) & 15);
    gload16(wsrc + row * K_ + p * 8, &Bs[i * 4096 + w * 512]);
  }

  // ---- A source pointers: chunk j writes LDS elems [j*4096 + t*8, +8)
  // row = j*16 + (t>>5); pq = t&31; lp = (pq&16)|((pq^row)&15); pl=lp>>1; qh=lp&1
  const float* asrc[8];
  {
    int pq = t & 31;
    int t5 = t >> 5;
#pragma unroll
    for (int j = 0; j < 8; ++j) {
      int row = j * 16 + t5;
      int lp = (pq & 16) | ((pq ^ row) & 15);
      int pl = lp >> 1, qh = lp & 1;
      int m = m0 + row;
      int b = m / MPT;
      int hw = m - b * MPT;
      int hp = hw / HP;
      int wp = hw - hp * HP;
      asrc[j] = x + ((size_t)(b * CIN + c) * IMG + hp * PS) * IMG + wp * PS
              + pl * IMG + qh * 8;
    }
  }

  // ---- issue all A loads (fp32) into regs
  float4 av0[8], av1[8];
#pragma unroll
  for (int j = 0; j < 8; ++j) {
    av0[j] = *(const float4*)(asrc[j]);
    av1[j] = *(const float4*)(asrc[j] + 4);
  }

  // ---- cvt + linear conflict-free ds_write
#pragma unroll
  for (int j = 0; j < 8; ++j) {
    union { ushort u[8]; uint4 v; } pk;
    pk.u[0] = f2bf(av0[j].x); pk.u[1] = f2bf(av0[j].y);
    pk.u[2] = f2bf(av0[j].z); pk.u[3] = f2bf(av0[j].w);
    pk.u[4] = f2bf(av1[j].x); pk.u[5] = f2bf(av1[j].y);
    pk.u[6] = f2bf(av1[j].z); pk.u[7] = f2bf(av1[j].w);
    *(uint4*)&As[j * 4096 + t * 8] = pk.v;
  }

  __syncthreads();   // the ONLY barrier

  f32x4 acc[4][2] = {};
#pragma unroll
  for (int kk8 = 0; kk8 < 32; kk8 += 4) {
    int lp = kk8 + h;
    bf16x8 af[4], bq[2];
#pragma unroll
    for (int mi = 0; mi < 4; ++mi) {
      int r = wr * 64 + mi * 16 + rB;
      int pp = (lp & 16) | ((lp ^ r) & 15);
      af[mi] = *(const bf16x8*)&As[r * 256 + pp * 8];
    }
#pragma unroll
    for (int ni = 0; ni < 2; ++ni) {
      int r = wc * 32 + ni * 16 + rB;
      int pp = (lp & 16) | ((lp ^ r) & 15);
      bq[ni] = *(const bf16x8*)&Bs[r * 256 + pp * 8];
    }
#pragma unroll
    for (int mi = 0; mi < 4; ++mi)
#pragma unroll
      for (int ni = 0; ni < 2; ++ni)
        acc[mi][ni] = __builtin_amdgcn_mfma_f32_16x16x32_bf16(af[mi], bq[ni], acc[mi][ni], 0, 0, 0);
  }

  // ---- epilogue: + bias.  C/D: col = lane&15, row = (lane>>4)*4 + reg
  float bv[2];
#pragma unroll
  for (int ni = 0; ni < 2; ++ni)
    bv[ni] = bias[c * D_ + n0 + wc * 32 + ni * 16 + rB];
#pragma unroll
  for (int mi = 0; mi < 4; ++mi) {
#pragma unroll
    for (int r = 0; r < 4; ++r) {
      int mrow = m0 + wr * 64 + mi * 16 + h * 4 + r;
      int b2 = mrow / MPT;
      int hw2 = mrow - b2 * MPT;
      float* op = out + ((size_t)b2 * (CIN * MPT) + c * MPT + hw2) * D_ + n0 + wc * 32 + rB;
#pragma unroll
      for (int ni = 0; ni < 2; ++ni)
        op[ni * 16] = acc[mi][ni][r] + bv[ni];
    }
  }
}

extern "C" void kernel_launch(void* const* d_in, const int* in_sizes, int n_in,
                              void* d_out, int out_size, void* d_ws, size_t ws_size,
                              hipStream_t stream) {
  const float* x  = (const float*)d_in[0];
  const float* ce = (const float*)d_in[2];
  const float* w1 = (const float*)d_in[3];
  const float* b1 = (const float*)d_in[4];
  const float* w2 = (const float*)d_in[5];
  const float* b2 = (const float*)d_in[6];
  float* out = (float*)d_out;

  char* ws = (char*)d_ws;
  float*  ht      = (float*)ws;                    // 128*8*4   = 4096 B  (transposed h)
  float*  biasOut = (float*)(ws + 4096);           // 8*768*4   = 24576 B
  ushort* wbf     = (ushort*)(ws + 4096 + 24576);  // 8*196608*2 = 3145728 B

  k1_fc1<<<dim3(CIN), dim3(512), 0, stream>>>(ce, w1, b1, ht);
  k2_fc2<<<dim3(NJ / 256), dim3(256), 0, stream>>>(ht, w2, b2, wbf, biasOut);
  k3_gemm<<<dim3(8 * 49 * 6), dim3(512), 0, stream>>>(x, wbf, biasOut, out);
}

// Round 5
// 109.780 us; speedup vs baseline: 1.3456x; 1.0211x over previous
//
#include <hip/hip_runtime.h>
#include <hip/hip_bf16.h>

#define CIN 8
#define IMG 224
#define PS 16
#define HP 14
#define D_ 768
#define HID 128
#define MPT 196      // Hp*Wp
#define K_ 256       // PS*PS
#define WSIZE 196608 // D_*K_
#define NJ 197376    // WSIZE + D_
#define BK 64

typedef __bf16 bf16x8 __attribute__((ext_vector_type(8)));
typedef float f32x4 __attribute__((ext_vector_type(4)));

static __device__ __forceinline__ ushort f2bf(float f) {
  union { float f; unsigned int u; } x; x.f = f;
  unsigned int r = x.u + 0x7fffu + ((x.u >> 16) & 1u);
  return (ushort)(r >> 16);
}

// async global -> LDS, 16B per lane. LDS base wave-uniform; global addr per-lane.
static __device__ __forceinline__ void gload16(const void* g, void* l) {
  __builtin_amdgcn_global_load_lds(
      (const __attribute__((address_space(1))) unsigned int*)(uintptr_t)g,
      (__attribute__((address_space(3))) unsigned int*)(uintptr_t)l, 16, 0, 0);
}

// ---------- k1: ht[i][c] = relu(ce @ fc1_w + b1), 4-way K-split per block
__global__ __launch_bounds__(512) void k1_fc1(const float* __restrict__ ce,
                                              const float* __restrict__ w1,
                                              const float* __restrict__ b1,
                                              float* __restrict__ ht) {
  __shared__ float sh[3][HID];
  int c = blockIdx.x;
  int t = threadIdx.x;
  int i = t & 127, ksp = t >> 7;
  const float* cev = ce + c * D_ + ksp * 192;
  const float* wp = w1 + (size_t)(ksp * 192) * HID + i;
  float acc = 0.f;
#pragma unroll 8
  for (int d = 0; d < 192; ++d) acc = fmaf(cev[d], wp[(size_t)d * HID], acc);
  if (ksp) sh[ksp - 1][i] = acc;
  __syncthreads();
  if (ksp == 0) {
    float s = b1[i] + acc + sh[0][i] + sh[1][i] + sh[2][i];
    ht[i * CIN + c] = fmaxf(s, 0.f);
  }
}

// ---------- k2: y = tanh(h@fc2_w + b2); scatter wts(bf16, [c][d*256+k]) + bias(fp32)
__global__ __launch_bounds__(256) void k2_fc2(
    const float* __restrict__ ht, const float* __restrict__ w2,
    const float* __restrict__ b2, ushort* __restrict__ wbf,
    float* __restrict__ biasOut) {
  int t = threadIdx.x;
  int j = blockIdx.x * 256 + t;
  const float* wp = w2 + j;
  const float4* ht4 = (const float4*)ht;  // uniform index -> scalar loads
  float4 a0 = {0, 0, 0, 0}, a1 = {0, 0, 0, 0};
#pragma unroll 8
  for (int i = 0; i < HID; ++i) {
    float wv = wp[(size_t)i * NJ];
    float4 hA = ht4[i * 2], hB = ht4[i * 2 + 1];
    a0.x = fmaf(hA.x, wv, a0.x); a0.y = fmaf(hA.y, wv, a0.y);
    a0.z = fmaf(hA.z, wv, a0.z); a0.w = fmaf(hA.w, wv, a0.w);
    a1.x = fmaf(hB.x, wv, a1.x); a1.y = fmaf(hB.y, wv, a1.y);
    a1.z = fmaf(hB.z, wv, a1.z); a1.w = fmaf(hB.w, wv, a1.w);
  }
  float bb = b2[j];
  if (j < WSIZE) {
    wbf[(size_t)0 * WSIZE + j] = f2bf(tanhf(a0.x + bb));
    wbf[(size_t)1 * WSIZE + j] = f2bf(tanhf(a0.y + bb));
    wbf[(size_t)2 * WSIZE + j] = f2bf(tanhf(a0.z + bb));
    wbf[(size_t)3 * WSIZE + j] = f2bf(tanhf(a0.w + bb));
    wbf[(size_t)4 * WSIZE + j] = f2bf(tanhf(a1.x + bb));
    wbf[(size_t)5 * WSIZE + j] = f2bf(tanhf(a1.y + bb));
    wbf[(size_t)6 * WSIZE + j] = f2bf(tanhf(a1.z + bb));
    wbf[(size_t)7 * WSIZE + j] = f2bf(tanhf(a1.w + bb));
  } else {
    int jb = j - WSIZE;
    biasOut[0 * D_ + jb] = tanhf(a0.x + bb);
    biasOut[1 * D_ + jb] = tanhf(a0.y + bb);
    biasOut[2 * D_ + jb] = tanhf(a0.z + bb);
    biasOut[3 * D_ + jb] = tanhf(a0.w + bb);
    biasOut[4 * D_ + jb] = tanhf(a1.x + bb);
    biasOut[5 * D_ + jb] = tanhf(a1.y + bb);
    biasOut[6 * D_ + jb] = tanhf(a1.z + bb);
    biasOut[7 * D_ + jb] = tanhf(a1.w + bb);
  }
}

// ---------- k3: per-channel GEMM, 128x128 tile, BK=64 x 4 steps.
// A: coalesced fp32 loads -> cvt -> swizzled ds_write (single buffer, between barriers).
// B: global_load_lds, double-buffered, source-swizzled (rule 21).
// Loads for step ks+1 issued AFTER the barriers -> latency hides under compute(ks).
// Swizzle involution (A and B): physical part = logical part ^ (row & 7).
__global__ __launch_bounds__(256, 3) void k3_gemm(
    const float* __restrict__ x, const ushort* __restrict__ wbf,
    const float* __restrict__ bias, float* __restrict__ out) {
  __shared__ ushort As[128 * BK];       // 16 KB
  __shared__ ushort Bs[2][128 * BK];    // 32 KB

  int bid = blockIdx.x;
  int c = bid & 7;            // channel == XCD
  int rem = bid >> 3;
  int mt = rem / 6;
  int nt = rem - mt * 6;      // 6 siblings share A rows within one XCD
  int m0 = mt * 128, n0 = nt * 128;

  int t = threadIdx.x;
  int lane = t & 63;
  int w = t >> 6;
  int wr = w >> 1, wc = w & 1;   // 2x2 wave grid, 64x64 per wave
  int rB = lane & 15;
  int h = lane >> 4;

  const ushort* wsrc = wbf + (size_t)c * WSIZE + (size_t)n0 * K_;

  // ---- B staging source pointers (per lane; +ks*BK per step)
  const ushort* bsrc[4];
#pragma unroll
  for (int i = 0; i < 4; ++i) {
    int idx = i * 256 + t;
    int row = idx >> 3;           // 8 lanes per row (64 el = 8 parts of 8)
    int q = idx & 7;              // physical part
    int p = q ^ (row & 7);        // logical part (inverse swizzle on source)
    bsrc[i] = wsrc + row * K_ + p * 8;
  }

  // ---- A source: thread handles rows m_l, p-rows {p_sel*2, p_sel*2+1} of each step
  int m_l = t & 127;
  int p_sel = t >> 7;
  const float* ab;
  {
    int m = m0 + m_l;
    int b = m / MPT;
    int hw = m - b * MPT;
    int hp = hw / HP;
    int wp = hw - hp * HP;
    ab = x + ((size_t)(b * CIN + c) * IMG + hp * PS) * IMG + wp * PS + p_sel * 2 * IMG;
  }

  // ---- prologue: issue B(0) and A(0)
#pragma unroll
  for (int i = 0; i < 4; ++i)
    gload16(bsrc[i], &Bs[0][(i * 256 + w * 64) * 8]);
  float4 pa[2][4];
#pragma unroll
  for (int j = 0; j < 2; ++j)
#pragma unroll
    for (int v = 0; v < 4; ++v)
      pa[j][v] = *(const float4*)(ab + j * IMG + v * 4);

  f32x4 acc[4][4] = {};
  int m7 = m_l & 7;
  int ptb = p_sel * 4;   // logical part base: (p_sel*2 + j)*2 = ptb + j*2

#pragma unroll
  for (int ks = 0; ks < 4; ++ks) {
    __syncthreads();   // As free (prev compute done); B(ks)/A(ks) landed
    // ---- cvt + swizzled ds_write of A(ks)
#pragma unroll
    for (int j = 0; j < 2; ++j) {
      union { ushort u[8]; uint4 v; } lo, hi;
      lo.u[0] = f2bf(pa[j][0].x); lo.u[1] = f2bf(pa[j][0].y);
      lo.u[2] = f2bf(pa[j][0].z); lo.u[3] = f2bf(pa[j][0].w);
      lo.u[4] = f2bf(pa[j][1].x); lo.u[5] = f2bf(pa[j][1].y);
      lo.u[6] = f2bf(pa[j][1].z); lo.u[7] = f2bf(pa[j][1].w);
      hi.u[0] = f2bf(pa[j][2].x); hi.u[1] = f2bf(pa[j][2].y);
      hi.u[2] = f2bf(pa[j][2].z); hi.u[3] = f2bf(pa[j][2].w);
      hi.u[4] = f2bf(pa[j][3].x); hi.u[5] = f2bf(pa[j][3].y);
      hi.u[6] = f2bf(pa[j][3].z); hi.u[7] = f2bf(pa[j][3].w);
      *(uint4*)&As[m_l * BK + ((ptb + j * 2)     ^ m7) * 8] = lo.v;
      *(uint4*)&As[m_l * BK + ((ptb + j * 2 + 1) ^ m7) * 8] = hi.v;
    }
    __syncthreads();   // As visible
    // ---- prefetch next step (issued after barriers -> overlaps compute below)
    if (ks < 3) {
#pragma unroll
      for (int i = 0; i < 4; ++i)
        gload16(bsrc[i] + (ks + 1) * BK, &Bs[(ks + 1) & 1][(i * 256 + w * 64) * 8]);
#pragma unroll
      for (int j = 0; j < 2; ++j)
#pragma unroll
        for (int v = 0; v < 4; ++v)
          pa[j][v] = *(const float4*)(ab + (ks + 1) * 4 * IMG + j * IMG + v * 4);
    }
    // ---- compute step ks
    const ushort* Bcur = Bs[ks & 1];
#pragma unroll
    for (int kc = 0; kc < 2; ++kc) {
      int lp = kc * 4 + h;
      bf16x8 af[4], bq[4];
#pragma unroll
      for (int mi = 0; mi < 4; ++mi) {
        int r = wr * 64 + mi * 16 + rB;
        af[mi] = *(const bf16x8*)&As[r * BK + ((lp ^ (r & 7)) * 8)];
      }
#pragma unroll
      for (int ni = 0; ni < 4; ++ni) {
        int r = wc * 64 + ni * 16 + rB;
        bq[ni] = *(const bf16x8*)&Bcur[r * BK + ((lp ^ (r & 7)) * 8)];
      }
#pragma unroll
      for (int mi = 0; mi < 4; ++mi)
#pragma unroll
        for (int ni = 0; ni < 4; ++ni)
          acc[mi][ni] = __builtin_amdgcn_mfma_f32_16x16x32_bf16(af[mi], bq[ni], acc[mi][ni], 0, 0, 0);
    }
  }

  // ---- epilogue: + bias.  C/D: col = lane&15, row = (lane>>4)*4 + reg
  float bv[4];
#pragma unroll
  for (int ni = 0; ni < 4; ++ni)
    bv[ni] = bias[c * D_ + n0 + wc * 64 + ni * 16 + rB];
#pragma unroll
  for (int mi = 0; mi < 4; ++mi) {
#pragma unroll
    for (int r = 0; r < 4; ++r) {
      int mrow = m0 + wr * 64 + mi * 16 + h * 4 + r;
      int b2 = mrow / MPT;
      int hw2 = mrow - b2 * MPT;
      float* op = out + ((size_t)b2 * (CIN * MPT) + c * MPT + hw2) * D_ + n0 + wc * 64 + rB;
#pragma unroll
      for (int ni = 0; ni < 4; ++ni)
        op[ni * 16] = acc[mi][ni][r] + bv[ni];
    }
  }
}

extern "C" void kernel_launch(void* const* d_in, const int* in_sizes, int n_in,
                              void* d_out, int out_size, void* d_ws, size_t ws_size,
                              hipStream_t stream) {
  const float* x  = (const float*)d_in[0];
  const float* ce = (const float*)d_in[2];
  const float* w1 = (const float*)d_in[3];
  const float* b1 = (const float*)d_in[4];
  const float* w2 = (const float*)d_in[5];
  const float* b2 = (const float*)d_in[6];
  float* out = (float*)d_out;

  char* ws = (char*)d_ws;
  float*  ht      = (float*)ws;                    // 128*8*4   = 4096 B  (transposed h)
  float*  biasOut = (float*)(ws + 4096);           // 8*768*4   = 24576 B
  ushort* wbf     = (ushort*)(ws + 4096 + 24576);  // 8*196608*2 = 3145728 B

  k1_fc1<<<dim3(CIN), dim3(512), 0, stream>>>(ce, w1, b1, ht);
  k2_fc2<<<dim3(NJ / 256), dim3(256), 0, stream>>>(ht, w2, b2, wbf, biasOut);
  k3_gemm<<<dim3(8 * 49 * 6), dim3(256), 0, stream>>>(x, wbf, biasOut, out);
}